// Round 5
// baseline (483.762 us; speedup 1.0000x reference)
//
#include <hip/hip_runtime.h>
#include <math.h>

#define S_SEQ 1024
#define NHEAD 16
#define HDIM  64
#define BATCH 4

typedef __attribute__((ext_vector_type(8))) short bf16x8;
typedef __attribute__((ext_vector_type(4))) float f32x4;

#define MFMA16 __builtin_amdgcn_mfma_f32_16x16x32_bf16

__device__ __forceinline__ float bf2f(unsigned short h) {
    union { unsigned u; float f; } un; un.u = ((unsigned)h) << 16; return un.f;
}
__device__ __forceinline__ unsigned short f2bf(float x) {
    union { float f; unsigned u; } un; un.f = x;
    unsigned r = un.u + 0x7FFFu + ((un.u >> 16) & 1u);
    return (unsigned short)(r >> 16);
}
__device__ __forceinline__ unsigned pack2bf(float a, float b) {
    return (unsigned)f2bf(a) | ((unsigned)f2bf(b) << 16);
}
__device__ __forceinline__ void glds16(const unsigned short* g, unsigned short* l) {
    __builtin_amdgcn_global_load_lds(
        (const __attribute__((address_space(1))) void*)g,
        (__attribute__((address_space(3))) void*)l, 16, 0, 0);
}

// ---------------------------------------------------------------------------
// Merged prep: fp32->bf16 conversion of hidden_states + dist_emb (block range
// [0, CONV_BLKS)) and Wq/Wk/Wv transpose+convert (blocks after that).
// ---------------------------------------------------------------------------
#define HS_F4 1048576   // 4*1024*1024 / 4
#define PE_F4 32752     // 2047*64 / 4
#define CONV_BLKS ((HS_F4 + PE_F4 + 255) / 256)

__global__ __launch_bounds__(256) void prep_kernel(
    const float* __restrict__ hs, const float* __restrict__ de,
    const float* __restrict__ Wq, const float* __restrict__ Wk,
    const float* __restrict__ Wv,
    unsigned short* __restrict__ hsb, unsigned short* __restrict__ peb,
    unsigned short* __restrict__ wt)
{
    __shared__ float tl[64 * 67];
    const int bx = blockIdx.x;
    const int t = threadIdx.x;

    if (bx < CONV_BLKS) {
        int i = bx * 256 + t;
        if (i < HS_F4) {
            float4 v = ((const float4*)hs)[i];
            uint2 o;
            o.x = pack2bf(v.x, v.y);
            o.y = pack2bf(v.z, v.w);
            *(uint2*)(hsb + 4 * (size_t)i) = o;
        } else if (i < HS_F4 + PE_F4) {
            int j = i - HS_F4;
            float4 v = ((const float4*)de)[j];
            uint2 o;
            o.x = pack2bf(v.x, v.y);
            o.y = pack2bf(v.z, v.w);
            *(uint2*)(peb + 4 * (size_t)j) = o;
        }
        return;
    }

    const int id = bx - CONV_BLKS;
    const int which = id >> 8;
    const int rem = id & 255;
    const float* W = (which == 0) ? Wq : (which == 1) ? Wk : Wv;
    unsigned short* outp = wt + (size_t)which * 1024 * 1024;
    const int k0 = (rem >> 4) * 64, n0 = (rem & 15) * 64;

#pragma unroll
    for (int it = 0; it < 4; ++it) {
        int idx = t + it * 256;
        int kr = idx >> 4;
        int c4 = (idx & 15) << 2;
        float4 v = *(const float4*)(W + (size_t)(k0 + kr) * 1024 + n0 + c4);
        tl[kr * 67 + c4 + 0] = v.x; tl[kr * 67 + c4 + 1] = v.y;
        tl[kr * 67 + c4 + 2] = v.z; tl[kr * 67 + c4 + 3] = v.w;
    }
    __syncthreads();
#pragma unroll
    for (int it = 0; it < 2; ++it) {
        int idx = t + it * 256;
        int nr = idx >> 3;
        int k8 = (idx & 7) << 3;
        unsigned short r[8];
#pragma unroll
        for (int e = 0; e < 8; ++e) r[e] = f2bf(tl[(k8 + e) * 67 + nr]);
        uint4 o;
        o.x = (unsigned)r[0] | ((unsigned)r[1] << 16);
        o.y = (unsigned)r[2] | ((unsigned)r[3] << 16);
        o.z = (unsigned)r[4] | ((unsigned)r[5] << 16);
        o.w = (unsigned)r[6] | ((unsigned)r[7] << 16);
        *(uint4*)(outp + (size_t)(n0 + nr) * 1024 + k0 + k8) = o;
    }
}

// ---------------------------------------------------------------------------
// QKV GEMM, m97-style staging.
//   which==2 (v): normal orientation, written TRANSPOSED per head [b,h,d,s]
//                 via uint2 (4 consecutive s at fixed d).
//   which<2 (q,k): TRANSPOSED mfma (swap operands) so each lane holds 4
//                 consecutive hd at fixed s -> coalesced uint2 stores into
//                 [b,h,s,hd]. q additionally pre-scaled by 0.125 (=1/sqrt(64)).
// ---------------------------------------------------------------------------
__global__ __launch_bounds__(256, 3) void qkv_mfma_kernel(
    const unsigned short* __restrict__ hsb, const unsigned short* __restrict__ wt,
    const float* __restrict__ bq, const float* __restrict__ bk,
    const float* __restrict__ bv,
    unsigned short* __restrict__ qo, unsigned short* __restrict__ ko,
    unsigned short* __restrict__ vo)
{
    __shared__ unsigned short As[128 * 64];
    __shared__ unsigned short Bs[128 * 64];

    const int t = threadIdx.x;
    const int lane = t & 63, w = t >> 6;
    const int l16 = lane & 15, quad = lane >> 4;
    const int wm = w >> 1, wn = w & 1;
    const int lrow = lane >> 3, cs = lane & 7;
    const int n0 = blockIdx.x * 128, m0 = blockIdx.y * 128;
    const int which = blockIdx.z;
    const unsigned short* wts = wt + (size_t)which * 1024 * 1024;
    const float* bias = (which == 0) ? bq : (which == 1) ? bk : bv;

    f32x4 acc[4][4];
#pragma unroll
    for (int i = 0; i < 4; ++i)
#pragma unroll
        for (int j = 0; j < 4; ++j) acc[i][j] = (f32x4){0.f, 0.f, 0.f, 0.f};

    for (int kk = 0; kk < 1024; kk += 64) {
#pragma unroll
        for (int it = 0; it < 4; ++it) {
            int mrow = 32 * w + 8 * it + lrow;
            int kch = cs ^ (mrow & 7);
            glds16(hsb + (size_t)(m0 + mrow) * 1024 + kk + kch * 8,
                   &As[(32 * w + 8 * it) * 64]);
            glds16(wts + (size_t)(n0 + mrow) * 1024 + kk + kch * 8,
                   &Bs[(32 * w + 8 * it) * 64]);
        }
        __syncthreads();

        bf16x8 af[4][2], bf[4][2];
#pragma unroll
        for (int i = 0; i < 4; ++i) {
            int am = 64 * wm + 16 * i + l16;
            int base = am * 64;
            af[i][0] = *(bf16x8*)&As[base + ((quad ^ (am & 7)) << 3)];
            af[i][1] = *(bf16x8*)&As[base + (((quad + 4) ^ (am & 7)) << 3)];
        }
#pragma unroll
        for (int j = 0; j < 4; ++j) {
            int bn = 64 * wn + 16 * j + l16;
            int base = bn * 64;
            bf[j][0] = *(bf16x8*)&Bs[base + ((quad ^ (bn & 7)) << 3)];
            bf[j][1] = *(bf16x8*)&Bs[base + (((quad + 4) ^ (bn & 7)) << 3)];
        }
        if (which == 2) {
#pragma unroll
            for (int i = 0; i < 4; ++i)
#pragma unroll
                for (int j = 0; j < 4; ++j) {
                    acc[i][j] = MFMA16(af[i][0], bf[j][0], acc[i][j], 0, 0, 0);
                    acc[i][j] = MFMA16(af[i][1], bf[j][1], acc[i][j], 0, 0, 0);
                }
        } else {
#pragma unroll
            for (int i = 0; i < 4; ++i)
#pragma unroll
                for (int j = 0; j < 4; ++j) {
                    acc[i][j] = MFMA16(bf[j][0], af[i][0], acc[i][j], 0, 0, 0);
                    acc[i][j] = MFMA16(bf[j][1], af[i][1], acc[i][j], 0, 0, 0);
                }
        }
        __syncthreads();
    }

    if (which == 2) {
        // acc[i][j]: rows m = m0+64wm+16i+4q+{0..3}, col n = n0+64wn+16j+l16
#pragma unroll
        for (int j = 0; j < 4; ++j) {
            int n = n0 + 64 * wn + 16 * j + l16;
            float bvv = bias[n];
            int hh = n >> 6, hd = n & 63;
#pragma unroll
            for (int i = 0; i < 4; ++i) {
                int mb = m0 + 64 * wm + 16 * i + 4 * quad;
                int bb = mb >> 10, s = mb & 1023;
                uint2 o;
                o.x = pack2bf(acc[i][j][0] + bvv, acc[i][j][1] + bvv);
                o.y = pack2bf(acc[i][j][2] + bvv, acc[i][j][3] + bvv);
                *(uint2*)(vo + ((size_t)(bb * NHEAD + hh) * HDIM + hd) * S_SEQ + s) = o;
            }
        }
    } else {
        // transposed: acc[i][j]: rows n = n0+64wn+16j+4q+{0..3}, col m = ...+16i+l16
        unsigned short* outp = (which == 0) ? qo : ko;
        const float qs = (which == 0) ? 0.125f : 1.0f;
#pragma unroll
        for (int j = 0; j < 4; ++j) {
            int nb = n0 + 64 * wn + 16 * j + 4 * quad;
            float4 b4 = *(const float4*)(bias + nb);
            int hh = nb >> 6, hd = nb & 63;
#pragma unroll
            for (int i = 0; i < 4; ++i) {
                int m = m0 + 64 * wm + 16 * i + l16;
                int bb = m >> 10, s = m & 1023;
                uint2 o;
                o.x = pack2bf((acc[i][j][0] + b4.x) * qs, (acc[i][j][1] + b4.y) * qs);
                o.y = pack2bf((acc[i][j][2] + b4.z) * qs, (acc[i][j][3] + b4.w) * qs);
                *(uint2*)(outp + ((size_t)(bb * NHEAD + hh) * S_SEQ + s) * HDIM + hd) = o;
            }
        }
    }
}

// ---------------------------------------------------------------------------
// Fused attention: r2 structure (2 barriers/tile, 4 blocks/CU) with VALU cuts:
//   - pes ring 96 -> 128 slots: all wraps become &127 (no branches).
//   - q pre-scaled 0.125 at QKV; KD scaled 0.125 at production -> score
//     assembly is pure adds (sc = accS + qd + kd + hm, hm = 0.5*hv + mv).
//   - s_setprio(1) around the phase-A MFMA cluster (T5).
//   LDS 40 KB -> 4 blocks/CU.
// ---------------------------------------------------------------------------
__global__ __launch_bounds__(256, 4) void attn_mfma_kernel(
    const unsigned short* __restrict__ qw, const unsigned short* __restrict__ kw,
    const unsigned short* __restrict__ vtw, const unsigned short* __restrict__ peb,
    const float* __restrict__ hyp, const float* __restrict__ mask,
    float* __restrict__ out)
{
    __shared__ unsigned short pes[128 * 64];   // pe ring [slot][d], swizzled chunks
    __shared__ unsigned short QDs[64 * 100];   // [l][(ar - l) mod 96]
    __shared__ unsigned short KDs[96 * 36];    // [di + r - 16][r]
    __shared__ unsigned short ps[64 * 32];     // probs [l][r], swizzled chunks

    const int t = threadIdx.x;
    const int lane = t & 63, w = t >> 6;
    const int l16 = lane & 15, quad = lane >> 4;
    const int lL = 16 * w + l16;               // lane's local q-row
    const int l0 = blockIdx.x * 64;
    const int h = blockIdx.y, b = blockIdx.z;

    const unsigned short* qb = qw + ((size_t)(b * NHEAD + h) * S_SEQ + l0) * HDIM;
    const unsigned short* kb = kw + (size_t)(b * NHEAD + h) * S_SEQ * HDIM;
    const unsigned short* vtb = vtw + (size_t)(b * NHEAD + h) * HDIM * S_SEQ;
    const float* hypb = hyp + (size_t)b * S_SEQ * S_SEQ + (size_t)(l0 + lL) * S_SEQ;
    const float* maskb = mask + b * S_SEQ;

    const bf16x8 qf0 = *(const bf16x8*)(qb + lL * 64 + quad * 8);
    const bf16x8 qf1 = *(const bf16x8*)(qb + lL * 64 + 32 + quad * 8);

    const int pb0 = l0 + 992;
    int sbP = pb0 & 127;                 // pes ring base (128 slots)
    int sbQ = pb0 % 96;                  // QD ring base
    int cQ = (pb0 - lL) % 96;            // QD per-lane col base

    const int strow = t >> 3, stp = t & 7;   // pe staging position
    const int swzl = (lL >> 1) & 3;          // ps chunk swizzle

    const int fstart = (w < 2) ? 3 * w : 2 * w + 2;   // KD frag split 3,3,2,2
    const int fcnt   = (w < 2) ? 3 : 2;

    f32x4 accO[4];
#pragma unroll
    for (int jf = 0; jf < 4; ++jf) accO[jf] = (f32x4){0.f, 0.f, 0.f, 0.f};
    float m_run = -INFINITY, lsum = 0.f;

    // ---- prime pe ring: abs rows [pb0+32, pb0+96) ----
#pragma unroll
    for (int it = 0; it < 2; ++it) {
        int idx = t + it * 256;
        int row = idx >> 3, p = idx & 7;
        int ar = pb0 + 32 + row;
        int slot = ar & 127;
        int src = ar > 2046 ? 2046 : ar;
        *(uint4*)&pes[slot * 64 + (p << 3)] =
            *(const uint4*)(peb + (size_t)src * 64 + ((p ^ (ar & 7)) << 3));
    }
    __syncthreads();

    // ---- prime QD for ar in [pb0+32, pb0+96) ----
#pragma unroll
    for (int jd = 0; jd < 4; ++jd) {
        int s = (sbP + 32 + 16 * jd + l16) & 127;
        const int sw = s & 7;
        bf16x8 p0 = *(bf16x8*)&pes[s * 64 + ((quad ^ sw) << 3)];
        bf16x8 p1 = *(bf16x8*)&pes[s * 64 + (((quad + 4) ^ sw) << 3)];
        f32x4 aq = (f32x4){0.f, 0.f, 0.f, 0.f};
        aq = MFMA16(p0, qf0, aq, 0, 0, 0);
        aq = MFMA16(p1, qf1, aq, 0, 0, 0);
        int cb = cQ + 32 + 16 * jd + 4 * quad;
#pragma unroll
        for (int i = 0; i < 4; ++i) {
            int c = cb + i; if (c >= 96) c -= 96;
            QDs[lL * 100 + c] = f2bf(aq[i]);
        }
    }

    // ---- prologue prefetch: kf(kt=0), peReg rows [pb0, pb0+32) ----
    bf16x8 kfC0 = *(const bf16x8*)(kb + (size_t)l16 * 64 + quad * 8);
    bf16x8 kfC1 = *(const bf16x8*)(kb + (size_t)l16 * 64 + 32 + quad * 8);
    bf16x8 kfC2 = *(const bf16x8*)(kb + (size_t)(16 + l16) * 64 + quad * 8);
    bf16x8 kfC3 = *(const bf16x8*)(kb + (size_t)(16 + l16) * 64 + 32 + quad * 8);
    uint4 peReg;
    {
        int ar = pb0 + strow;
        peReg = *(const uint4*)(peb + (size_t)ar * 64 + ((stp ^ (ar & 7)) << 3));
    }

    for (int kt = 0; kt < 32; ++kt) {
        const int r0 = 32 * kt;

        // ---- hyp/mask loads for this tile ----
        const float4 hv0 = *(const float4*)(hypb + r0 + 4 * quad);
        const float4 hv1 = *(const float4*)(hypb + r0 + 16 + 4 * quad);
        const float4 mv0 = *(const float4*)(maskb + r0 + 4 * quad);
        const float4 mv1 = *(const float4*)(maskb + r0 + 16 + 4 * quad);

        // ---- stage 32 new pe rows [pb, pb+32) from prefetched reg ----
        {
            int slot = (sbP + strow) & 127;
            *(uint4*)&pes[slot * 64 + (stp << 3)] = peReg;
        }
        __syncthreads();

        // ================= phase A =================
        __builtin_amdgcn_s_setprio(1);
        f32x4 accS0 = (f32x4){0.f, 0.f, 0.f, 0.f};
        f32x4 accS1 = (f32x4){0.f, 0.f, 0.f, 0.f};
        accS0 = MFMA16(kfC0, qf0, accS0, 0, 0, 0);
        accS0 = MFMA16(kfC1, qf1, accS0, 0, 0, 0);
        accS1 = MFMA16(kfC2, qf0, accS1, 0, 0, 0);
        accS1 = MFMA16(kfC3, qf1, accS1, 0, 0, 0);

        // QD: 32 new ar rows [pb, pb+32), own-l output
#pragma unroll
        for (int jd = 0; jd < 2; ++jd) {
            int s = (sbP + 16 * jd + l16) & 127;
            const int sw = s & 7;
            bf16x8 p0 = *(bf16x8*)&pes[s * 64 + ((quad ^ sw) << 3)];
            bf16x8 p1 = *(bf16x8*)&pes[s * 64 + (((quad + 4) ^ sw) << 3)];
            f32x4 aq = (f32x4){0.f, 0.f, 0.f, 0.f};
            aq = MFMA16(p0, qf0, aq, 0, 0, 0);
            aq = MFMA16(p1, qf1, aq, 0, 0, 0);
            int cb = cQ + 16 * jd + 4 * quad;
#pragma unroll
            for (int i = 0; i < 4; ++i) {
                int c = cb + i; if (c >= 96) c -= 96;
                QDs[lL * 100 + c] = f2bf(aq[i]);
            }
        }

        // KD: lane -> (own r = rB + l16, di = diB + 4q + i); store [di+r-16][r]
#pragma unroll
        for (int jk = 0; jk < 3; ++jk) {
            if (jk < fcnt) {
                const int f = fstart + jk;
                const int diB = 16 * ((f + 1) >> 1);
                const int rB = (f & 1) ? 0 : 16;
                int s = (sbP + diB + l16) & 127;
                const int sw = s & 7;
                bf16x8 p0 = *(bf16x8*)&pes[s * 64 + ((quad ^ sw) << 3)];
                bf16x8 p1 = *(bf16x8*)&pes[s * 64 + (((quad + 4) ^ sw) << 3)];
                f32x4 ak = (f32x4){0.f, 0.f, 0.f, 0.f};
                if (rB == 0) {
                    ak = MFMA16(p0, kfC0, ak, 0, 0, 0);
                    ak = MFMA16(p1, kfC1, ak, 0, 0, 0);
                } else {
                    ak = MFMA16(p0, kfC2, ak, 0, 0, 0);
                    ak = MFMA16(p1, kfC3, ak, 0, 0, 0);
                }
                const int colr = rB + l16;
                const int aB = diB + colr + 4 * quad - 16;
#pragma unroll
                for (int i = 0; i < 4; ++i)
                    KDs[(aB + i) * 36 + colr] = f2bf(ak[i] * 0.125f);
            }
        }
        __builtin_amdgcn_s_setprio(0);
        __syncthreads();

        // ================= phase B =================
        // prefetch next tile's kf + pe staging reg (consumed next iteration)
        {
            const int r0n = (kt < 31) ? r0 + 32 : r0;
            kfC0 = *(const bf16x8*)(kb + (size_t)(r0n + l16) * 64 + quad * 8);
            kfC1 = *(const bf16x8*)(kb + (size_t)(r0n + l16) * 64 + 32 + quad * 8);
            kfC2 = *(const bf16x8*)(kb + (size_t)(r0n + 16 + l16) * 64 + quad * 8);
            kfC3 = *(const bf16x8*)(kb + (size_t)(r0n + 16 + l16) * 64 + 32 + quad * 8);
            // rows [pb', pb'+32) for next iteration's stage (pb' = pb0 - r0n).
            // kt==31: r0n==r0 -> ar in [l0, l0+32), in-bounds, unused.
            int ar = pb0 - r0n + strow;
            peReg = *(const uint4*)(peb + (size_t)ar * 64 + ((stp ^ (ar & 7)) << 3));
        }
        // v fragments for PV
        bf16x8 vvA[4];
#pragma unroll
        for (int jf = 0; jf < 4; ++jf)
            vvA[jf] = *(const bf16x8*)(vtb + (size_t)(16 * jf + l16) * S_SEQ +
                                       r0 + quad * 8);

        // gather bias (vector b64) + assemble scores (pure adds)
        float sc0[4], sc1[4];
        {
            uint2 qd2 = *(uint2*)&QDs[lL * 100 + sbQ + 28 - 4 * quad];
            uint2 kd2 = *(uint2*)&KDs[(lL + 15) * 36 + 4 * quad];
            float hm0 = fmaf(0.5f, hv0.x, mv0.x);
            float hm1 = fmaf(0.5f, hv0.y, mv0.y);
            float hm2 = fmaf(0.5f, hv0.z, mv0.z);
            float hm3 = fmaf(0.5f, hv0.w, mv0.w);
            sc0[0] = accS0[0] + bf2f((unsigned short)(qd2.y >> 16)) +
                     bf2f((unsigned short)(kd2.x & 0xffff)) + hm0;
            sc0[1] = accS0[1] + bf2f((unsigned short)(qd2.y & 0xffff)) +
                     bf2f((unsigned short)(kd2.x >> 16)) + hm1;
            sc0[2] = accS0[2] + bf2f((unsigned short)(qd2.x >> 16)) +
                     bf2f((unsigned short)(kd2.y & 0xffff)) + hm2;
            sc0[3] = accS0[3] + bf2f((unsigned short)(qd2.x & 0xffff)) +
                     bf2f((unsigned short)(kd2.y >> 16)) + hm3;
        }
        {
            uint2 qd2 = *(uint2*)&QDs[lL * 100 + sbQ + 12 - 4 * quad];
            uint2 kd2 = *(uint2*)&KDs[(lL + 15) * 36 + 16 + 4 * quad];
            float hm0 = fmaf(0.5f, hv1.x, mv1.x);
            float hm1 = fmaf(0.5f, hv1.y, mv1.y);
            float hm2 = fmaf(0.5f, hv1.z, mv1.z);
            float hm3 = fmaf(0.5f, hv1.w, mv1.w);
            sc1[0] = accS1[0] + bf2f((unsigned short)(qd2.y >> 16)) +
                     bf2f((unsigned short)(kd2.x & 0xffff)) + hm0;
            sc1[1] = accS1[1] + bf2f((unsigned short)(qd2.y & 0xffff)) +
                     bf2f((unsigned short)(kd2.x >> 16)) + hm1;
            sc1[2] = accS1[2] + bf2f((unsigned short)(qd2.x >> 16)) +
                     bf2f((unsigned short)(kd2.y & 0xffff)) + hm2;
            sc1[3] = accS1[3] + bf2f((unsigned short)(qd2.x & 0xffff)) +
                     bf2f((unsigned short)(kd2.y >> 16)) + hm3;
        }

        // ---- online softmax ----
        float mx = fmaxf(fmaxf(fmaxf(sc0[0], sc0[1]), fmaxf(sc0[2], sc0[3])),
                         fmaxf(fmaxf(sc1[0], sc1[1]), fmaxf(sc1[2], sc1[3])));
        mx = fmaxf(mx, __shfl_xor(mx, 16));
        mx = fmaxf(mx, __shfl_xor(mx, 32));
        const float m_new = fmaxf(m_run, mx);
        const float al = __expf(m_run - m_new);
        m_run = m_new;
        float rs = 0.f;
#pragma unroll
        for (int i = 0; i < 4; ++i) { sc0[i] = __expf(sc0[i] - m_new); rs += sc0[i]; }
#pragma unroll
        for (int i = 0; i < 4; ++i) { sc1[i] = __expf(sc1[i] - m_new); rs += sc1[i]; }
        rs += __shfl_xor(rs, 16);
        rs += __shfl_xor(rs, 32);
        lsum = lsum * al + rs;

        // ---- probs -> LDS (intra-wave only) ----
        {
            uint2 pw;
            pw.x = pack2bf(sc0[0], sc0[1]); pw.y = pack2bf(sc0[2], sc0[3]);
            *(uint2*)&ps[lL * 32 + (((quad >> 1) ^ swzl) << 3) + 4 * (quad & 1)] = pw;
            pw.x = pack2bf(sc1[0], sc1[1]); pw.y = pack2bf(sc1[2], sc1[3]);
            *(uint2*)&ps[lL * 32 + (((2 + (quad >> 1)) ^ swzl) << 3) + 4 * (quad & 1)] = pw;
        }

        // ---- PV ----
        const bf16x8 pf = *(const bf16x8*)&ps[lL * 32 + ((quad ^ swzl) << 3)];
        const float alv0 = __shfl(al, 4 * quad + 0);
        const float alv1 = __shfl(al, 4 * quad + 1);
        const float alv2 = __shfl(al, 4 * quad + 2);
        const float alv3 = __shfl(al, 4 * quad + 3);
#pragma unroll
        for (int jf = 0; jf < 4; ++jf) {
            f32x4 o = accO[jf];
            o[0] *= alv0; o[1] *= alv1; o[2] *= alv2; o[3] *= alv3;
            o = MFMA16(pf, vvA[jf], o, 0, 0, 0);
            accO[jf] = o;
        }

        sbP = (sbP - 32) & 127;
        sbQ -= 32; if (sbQ < 0) sbQ += 96;
        cQ -= 32; if (cQ < 0) cQ += 96;
    }

    // ---- epilogue ----
    const float ls0 = __shfl(lsum, 4 * quad + 0);
    const float ls1 = __shfl(lsum, 4 * quad + 1);
    const float ls2 = __shfl(lsum, 4 * quad + 2);
    const float ls3 = __shfl(lsum, 4 * quad + 3);
#pragma unroll
    for (int jf = 0; jf < 4; ++jf) {
        const size_t col = (size_t)h * 64 + 16 * jf + l16;
        float* ob = out + ((size_t)b * S_SEQ + l0 + 16 * w + 4 * quad) * 1024 + col;
        ob[0]        = accO[jf][0] / ls0;
        ob[1024]     = accO[jf][1] / ls1;
        ob[2048]     = accO[jf][2] / ls2;
        ob[3072]     = accO[jf][3] / ls3;
    }
}

extern "C" void kernel_launch(void* const* d_in, const int* in_sizes, int n_in,
                              void* d_out, int out_size, void* d_ws, size_t ws_size,
                              hipStream_t stream) {
    const float* hs   = (const float*)d_in[0];
    const float* mask = (const float*)d_in[1];
    const float* hyp  = (const float*)d_in[2];
    const float* Wq   = (const float*)d_in[3];
    const float* bq   = (const float*)d_in[4];
    const float* Wk   = (const float*)d_in[5];
    const float* bk   = (const float*)d_in[6];
    const float* Wv   = (const float*)d_in[7];
    const float* bv   = (const float*)d_in[8];
    const float* de   = (const float*)d_in[9];

    char* ws = (char*)d_ws;
    unsigned short* qw  = (unsigned short*)(ws);                    // 8 MB
    unsigned short* kw  = (unsigned short*)(ws + (8u << 20));       // 8 MB
    unsigned short* vtw = (unsigned short*)(ws + (16u << 20));      // 8 MB (v^T)
    unsigned short* hsb = (unsigned short*)(ws + (24u << 20));      // 8 MB
    unsigned short* wt  = (unsigned short*)(ws + (32u << 20));      // 6 MB
    unsigned short* peb = (unsigned short*)(ws + (38u << 20));      // 0.25 MB

    prep_kernel<<<dim3(CONV_BLKS + 768), 256, 0, stream>>>(hs, de, Wq, Wk, Wv,
                                                           hsb, peb, wt);
    qkv_mfma_kernel<<<dim3(8, 32, 3), 256, 0, stream>>>(hsb, wt, bq, bk, bv, qw, kw, vtw);
    attn_mfma_kernel<<<dim3(16, NHEAD, BATCH), 256, 0, stream>>>(
        qw, kw, vtw, peb, hyp, mask, (float*)d_out);
}

// Round 6
// 288.339 us; speedup vs baseline: 1.6778x; 1.6778x over previous
//
#include <hip/hip_runtime.h>
#include <math.h>

#define S_SEQ 1024
#define NHEAD 16
#define HDIM  64
#define BATCH 4

typedef __attribute__((ext_vector_type(8))) short bf16x8;
typedef __attribute__((ext_vector_type(4))) float f32x4;

#define MFMA16 __builtin_amdgcn_mfma_f32_16x16x32_bf16

__device__ __forceinline__ float bf2f(unsigned short h) {
    union { unsigned u; float f; } un; un.u = ((unsigned)h) << 16; return un.f;
}
__device__ __forceinline__ unsigned short f2bf(float x) {
    union { float f; unsigned u; } un; un.f = x;
    unsigned r = un.u + 0x7FFFu + ((un.u >> 16) & 1u);
    return (unsigned short)(r >> 16);
}
__device__ __forceinline__ unsigned pack2bf(float a, float b) {
    return (unsigned)f2bf(a) | ((unsigned)f2bf(b) << 16);
}
__device__ __forceinline__ void glds16(const unsigned short* g, unsigned short* l) {
    __builtin_amdgcn_global_load_lds(
        (const __attribute__((address_space(1))) void*)g,
        (__attribute__((address_space(3))) void*)l, 16, 0, 0);
}

// ---------------------------------------------------------------------------
// Merged prep: fp32->bf16 conversion of hidden_states + dist_emb (block range
// [0, CONV_BLKS)) and Wq/Wk/Wv transpose+convert (blocks after that).
// ---------------------------------------------------------------------------
#define HS_F4 1048576   // 4*1024*1024 / 4
#define PE_F4 32752     // 2047*64 / 4
#define CONV_BLKS ((HS_F4 + PE_F4 + 255) / 256)

__global__ __launch_bounds__(256) void prep_kernel(
    const float* __restrict__ hs, const float* __restrict__ de,
    const float* __restrict__ Wq, const float* __restrict__ Wk,
    const float* __restrict__ Wv,
    unsigned short* __restrict__ hsb, unsigned short* __restrict__ peb,
    unsigned short* __restrict__ wt)
{
    __shared__ float tl[64 * 67];
    const int bx = blockIdx.x;
    const int t = threadIdx.x;

    if (bx < CONV_BLKS) {
        int i = bx * 256 + t;
        if (i < HS_F4) {
            float4 v = ((const float4*)hs)[i];
            uint2 o;
            o.x = pack2bf(v.x, v.y);
            o.y = pack2bf(v.z, v.w);
            *(uint2*)(hsb + 4 * (size_t)i) = o;
        } else if (i < HS_F4 + PE_F4) {
            int j = i - HS_F4;
            float4 v = ((const float4*)de)[j];
            uint2 o;
            o.x = pack2bf(v.x, v.y);
            o.y = pack2bf(v.z, v.w);
            *(uint2*)(peb + 4 * (size_t)j) = o;
        }
        return;
    }

    const int id = bx - CONV_BLKS;
    const int which = id >> 8;
    const int rem = id & 255;
    const float* W = (which == 0) ? Wq : (which == 1) ? Wk : Wv;
    unsigned short* outp = wt + (size_t)which * 1024 * 1024;
    const int k0 = (rem >> 4) * 64, n0 = (rem & 15) * 64;

#pragma unroll
    for (int it = 0; it < 4; ++it) {
        int idx = t + it * 256;
        int kr = idx >> 4;
        int c4 = (idx & 15) << 2;
        float4 v = *(const float4*)(W + (size_t)(k0 + kr) * 1024 + n0 + c4);
        tl[kr * 67 + c4 + 0] = v.x; tl[kr * 67 + c4 + 1] = v.y;
        tl[kr * 67 + c4 + 2] = v.z; tl[kr * 67 + c4 + 3] = v.w;
    }
    __syncthreads();
#pragma unroll
    for (int it = 0; it < 2; ++it) {
        int idx = t + it * 256;
        int nr = idx >> 3;
        int k8 = (idx & 7) << 3;
        unsigned short r[8];
#pragma unroll
        for (int e = 0; e < 8; ++e) r[e] = f2bf(tl[(k8 + e) * 67 + nr]);
        uint4 o;
        o.x = (unsigned)r[0] | ((unsigned)r[1] << 16);
        o.y = (unsigned)r[2] | ((unsigned)r[3] << 16);
        o.z = (unsigned)r[4] | ((unsigned)r[5] << 16);
        o.w = (unsigned)r[6] | ((unsigned)r[7] << 16);
        *(uint4*)(outp + (size_t)(n0 + nr) * 1024 + k0 + k8) = o;
    }
}

// ---------------------------------------------------------------------------
// QKV GEMM, m97-style staging (r2 store paths restored).
//   XCD-aware work swizzle: XCD x (= lid%8) owns m-panels {4x..4x+3} for all
//   3 which and all 8 n-tiles -> A-panel and B stream stay L2-local.
//   q pre-scaled by 0.125 in the epilogue. v written transposed [b,h,d,s].
// ---------------------------------------------------------------------------
__global__ __launch_bounds__(256, 3) void qkv_mfma_kernel(
    const unsigned short* __restrict__ hsb, const unsigned short* __restrict__ wt,
    const float* __restrict__ bq, const float* __restrict__ bk,
    const float* __restrict__ bv,
    unsigned short* __restrict__ qo, unsigned short* __restrict__ ko,
    unsigned short* __restrict__ vo)
{
    __shared__ unsigned short As[128 * 64];
    __shared__ unsigned short Bs[128 * 64];

    const int t = threadIdx.x;
    const int lane = t & 63, w = t >> 6;
    const int l16 = lane & 15, quad = lane >> 4;
    const int wm = w >> 1, wn = w & 1;
    const int lrow = lane >> 3, cs = lane & 7;

    // ---- bijective XCD-aware swizzle (768 blocks, 96 per XCD) ----
    const int lid = blockIdx.x + 8 * blockIdx.y + 256 * blockIdx.z;
    const int x = lid & 7, pos = lid >> 3;       // pos in [0,96)
    const int pl = pos / 24, sub = pos - pl * 24;
    const int m0 = (4 * x + pl) * 128;           // m-panel 0..31
    const int which = sub >> 3;                  // 0..2
    const int n0 = (sub & 7) * 128;              // n-tile 0..7

    const unsigned short* wts = wt + (size_t)which * 1024 * 1024;
    const float* bias = (which == 0) ? bq : (which == 1) ? bk : bv;

    f32x4 acc[4][4];
#pragma unroll
    for (int i = 0; i < 4; ++i)
#pragma unroll
        for (int j = 0; j < 4; ++j) acc[i][j] = (f32x4){0.f, 0.f, 0.f, 0.f};

    for (int kk = 0; kk < 1024; kk += 64) {
#pragma unroll
        for (int it = 0; it < 4; ++it) {
            int mrow = 32 * w + 8 * it + lrow;
            int kch = cs ^ (mrow & 7);
            glds16(hsb + (size_t)(m0 + mrow) * 1024 + kk + kch * 8,
                   &As[(32 * w + 8 * it) * 64]);
            glds16(wts + (size_t)(n0 + mrow) * 1024 + kk + kch * 8,
                   &Bs[(32 * w + 8 * it) * 64]);
        }
        __syncthreads();

        bf16x8 af[4][2], bf[4][2];
#pragma unroll
        for (int i = 0; i < 4; ++i) {
            int am = 64 * wm + 16 * i + l16;
            int base = am * 64;
            af[i][0] = *(bf16x8*)&As[base + ((quad ^ (am & 7)) << 3)];
            af[i][1] = *(bf16x8*)&As[base + (((quad + 4) ^ (am & 7)) << 3)];
        }
#pragma unroll
        for (int j = 0; j < 4; ++j) {
            int bn = 64 * wn + 16 * j + l16;
            int base = bn * 64;
            bf[j][0] = *(bf16x8*)&Bs[base + ((quad ^ (bn & 7)) << 3)];
            bf[j][1] = *(bf16x8*)&Bs[base + (((quad + 4) ^ (bn & 7)) << 3)];
        }
#pragma unroll
        for (int i = 0; i < 4; ++i)
#pragma unroll
            for (int j = 0; j < 4; ++j) {
                acc[i][j] = MFMA16(af[i][0], bf[j][0], acc[i][j], 0, 0, 0);
                acc[i][j] = MFMA16(af[i][1], bf[j][1], acc[i][j], 0, 0, 0);
            }
        __syncthreads();
    }

    const float qs = (which == 0) ? 0.125f : 1.0f;
#pragma unroll
    for (int j = 0; j < 4; ++j) {
        int n = n0 + 64 * wn + 16 * j + l16;
        float bvv = bias[n];
        int hh = n >> 6, hd = n & 63;
#pragma unroll
        for (int i = 0; i < 4; ++i) {
            int mb = m0 + 64 * wm + 16 * i + 4 * quad;
            int bb = mb >> 10, s = mb & 1023;
            if (which == 2) {
                // v transposed: [b,h,d,s]; 4 consecutive s -> one uint2
                uint2 o;
                o.x = pack2bf(acc[i][j][0] + bvv, acc[i][j][1] + bvv);
                o.y = pack2bf(acc[i][j][2] + bvv, acc[i][j][3] + bvv);
                *(uint2*)(vo + ((size_t)(bb * NHEAD + hh) * HDIM + hd) * S_SEQ + s) = o;
            } else {
                unsigned short* outp = (which == 0) ? qo : ko;
#pragma unroll
                for (int r = 0; r < 4; ++r)
                    outp[((size_t)(bb * NHEAD + hh) * S_SEQ + s + r) * HDIM + hd] =
                        f2bf((acc[i][j][r] + bvv) * qs);
            }
        }
    }
}

// ---------------------------------------------------------------------------
// Fused attention: r2 structure (2 barriers/tile, 4 blocks/CU) with VALU cuts:
//   - pes ring 96 -> 128 slots: all wraps become &127 (no branches).
//   - q pre-scaled 0.125 at QKV; KD scaled 0.125 at production -> score
//     assembly is pure adds (sc = accS + qd + kd + hm, hm = 0.5*hv + mv).
//   - s_setprio(1) around the phase-A MFMA cluster (T5).
//   LDS 40 KB -> 4 blocks/CU.
// ---------------------------------------------------------------------------
__global__ __launch_bounds__(256, 4) void attn_mfma_kernel(
    const unsigned short* __restrict__ qw, const unsigned short* __restrict__ kw,
    const unsigned short* __restrict__ vtw, const unsigned short* __restrict__ peb,
    const float* __restrict__ hyp, const float* __restrict__ mask,
    float* __restrict__ out)
{
    __shared__ unsigned short pes[128 * 64];   // pe ring [slot][d], swizzled chunks
    __shared__ unsigned short QDs[64 * 100];   // [l][(ar - l) mod 96]
    __shared__ unsigned short KDs[96 * 36];    // [di + r - 16][r]
    __shared__ unsigned short ps[64 * 32];     // probs [l][r], swizzled chunks

    const int t = threadIdx.x;
    const int lane = t & 63, w = t >> 6;
    const int l16 = lane & 15, quad = lane >> 4;
    const int lL = 16 * w + l16;               // lane's local q-row
    const int l0 = blockIdx.x * 64;
    const int h = blockIdx.y, b = blockIdx.z;

    const unsigned short* qb = qw + ((size_t)(b * NHEAD + h) * S_SEQ + l0) * HDIM;
    const unsigned short* kb = kw + (size_t)(b * NHEAD + h) * S_SEQ * HDIM;
    const unsigned short* vtb = vtw + (size_t)(b * NHEAD + h) * HDIM * S_SEQ;
    const float* hypb = hyp + (size_t)b * S_SEQ * S_SEQ + (size_t)(l0 + lL) * S_SEQ;
    const float* maskb = mask + b * S_SEQ;

    const bf16x8 qf0 = *(const bf16x8*)(qb + lL * 64 + quad * 8);
    const bf16x8 qf1 = *(const bf16x8*)(qb + lL * 64 + 32 + quad * 8);

    const int pb0 = l0 + 992;
    int sbP = pb0 & 127;                 // pes ring base (128 slots)
    int sbQ = pb0 % 96;                  // QD ring base
    int cQ = (pb0 - lL) % 96;            // QD per-lane col base

    const int strow = t >> 3, stp = t & 7;   // pe staging position
    const int swzl = (lL >> 1) & 3;          // ps chunk swizzle

    const int fstart = (w < 2) ? 3 * w : 2 * w + 2;   // KD frag split 3,3,2,2
    const int fcnt   = (w < 2) ? 3 : 2;

    f32x4 accO[4];
#pragma unroll
    for (int jf = 0; jf < 4; ++jf) accO[jf] = (f32x4){0.f, 0.f, 0.f, 0.f};
    float m_run = -INFINITY, lsum = 0.f;

    // ---- prime pe ring: abs rows [pb0+32, pb0+96) ----
#pragma unroll
    for (int it = 0; it < 2; ++it) {
        int idx = t + it * 256;
        int row = idx >> 3, p = idx & 7;
        int ar = pb0 + 32 + row;
        int slot = ar & 127;
        int src = ar > 2046 ? 2046 : ar;
        *(uint4*)&pes[slot * 64 + (p << 3)] =
            *(const uint4*)(peb + (size_t)src * 64 + ((p ^ (ar & 7)) << 3));
    }
    __syncthreads();

    // ---- prime QD for ar in [pb0+32, pb0+96) ----
#pragma unroll
    for (int jd = 0; jd < 4; ++jd) {
        int s = (sbP + 32 + 16 * jd + l16) & 127;
        const int sw = s & 7;
        bf16x8 p0 = *(bf16x8*)&pes[s * 64 + ((quad ^ sw) << 3)];
        bf16x8 p1 = *(bf16x8*)&pes[s * 64 + (((quad + 4) ^ sw) << 3)];
        f32x4 aq = (f32x4){0.f, 0.f, 0.f, 0.f};
        aq = MFMA16(p0, qf0, aq, 0, 0, 0);
        aq = MFMA16(p1, qf1, aq, 0, 0, 0);
        int cb = cQ + 32 + 16 * jd + 4 * quad;
#pragma unroll
        for (int i = 0; i < 4; ++i) {
            int c = cb + i; if (c >= 96) c -= 96;
            QDs[lL * 100 + c] = f2bf(aq[i]);
        }
    }

    // ---- prologue prefetch: kf(kt=0), peReg rows [pb0, pb0+32) ----
    bf16x8 kfC0 = *(const bf16x8*)(kb + (size_t)l16 * 64 + quad * 8);
    bf16x8 kfC1 = *(const bf16x8*)(kb + (size_t)l16 * 64 + 32 + quad * 8);
    bf16x8 kfC2 = *(const bf16x8*)(kb + (size_t)(16 + l16) * 64 + quad * 8);
    bf16x8 kfC3 = *(const bf16x8*)(kb + (size_t)(16 + l16) * 64 + 32 + quad * 8);
    uint4 peReg;
    {
        int ar = pb0 + strow;
        peReg = *(const uint4*)(peb + (size_t)ar * 64 + ((stp ^ (ar & 7)) << 3));
    }

    for (int kt = 0; kt < 32; ++kt) {
        const int r0 = 32 * kt;

        // ---- hyp/mask loads for this tile ----
        const float4 hv0 = *(const float4*)(hypb + r0 + 4 * quad);
        const float4 hv1 = *(const float4*)(hypb + r0 + 16 + 4 * quad);
        const float4 mv0 = *(const float4*)(maskb + r0 + 4 * quad);
        const float4 mv1 = *(const float4*)(maskb + r0 + 16 + 4 * quad);

        // ---- stage 32 new pe rows [pb, pb+32) from prefetched reg ----
        {
            int slot = (sbP + strow) & 127;
            *(uint4*)&pes[slot * 64 + (stp << 3)] = peReg;
        }
        __syncthreads();

        // ================= phase A =================
        __builtin_amdgcn_s_setprio(1);
        f32x4 accS0 = (f32x4){0.f, 0.f, 0.f, 0.f};
        f32x4 accS1 = (f32x4){0.f, 0.f, 0.f, 0.f};
        accS0 = MFMA16(kfC0, qf0, accS0, 0, 0, 0);
        accS0 = MFMA16(kfC1, qf1, accS0, 0, 0, 0);
        accS1 = MFMA16(kfC2, qf0, accS1, 0, 0, 0);
        accS1 = MFMA16(kfC3, qf1, accS1, 0, 0, 0);

        // QD: 32 new ar rows [pb, pb+32), own-l output
#pragma unroll
        for (int jd = 0; jd < 2; ++jd) {
            int s = (sbP + 16 * jd + l16) & 127;
            const int sw = s & 7;
            bf16x8 p0 = *(bf16x8*)&pes[s * 64 + ((quad ^ sw) << 3)];
            bf16x8 p1 = *(bf16x8*)&pes[s * 64 + (((quad + 4) ^ sw) << 3)];
            f32x4 aq = (f32x4){0.f, 0.f, 0.f, 0.f};
            aq = MFMA16(p0, qf0, aq, 0, 0, 0);
            aq = MFMA16(p1, qf1, aq, 0, 0, 0);
            int cb = cQ + 16 * jd + 4 * quad;
#pragma unroll
            for (int i = 0; i < 4; ++i) {
                int c = cb + i; if (c >= 96) c -= 96;
                QDs[lL * 100 + c] = f2bf(aq[i]);
            }
        }

        // KD: lane -> (own r = rB + l16, di = diB + 4q + i); store [di+r-16][r]
#pragma unroll
        for (int jk = 0; jk < 3; ++jk) {
            if (jk < fcnt) {
                const int f = fstart + jk;
                const int diB = 16 * ((f + 1) >> 1);
                const int rB = (f & 1) ? 0 : 16;
                int s = (sbP + diB + l16) & 127;
                const int sw = s & 7;
                bf16x8 p0 = *(bf16x8*)&pes[s * 64 + ((quad ^ sw) << 3)];
                bf16x8 p1 = *(bf16x8*)&pes[s * 64 + (((quad + 4) ^ sw) << 3)];
                f32x4 ak = (f32x4){0.f, 0.f, 0.f, 0.f};
                if (rB == 0) {
                    ak = MFMA16(p0, kfC0, ak, 0, 0, 0);
                    ak = MFMA16(p1, kfC1, ak, 0, 0, 0);
                } else {
                    ak = MFMA16(p0, kfC2, ak, 0, 0, 0);
                    ak = MFMA16(p1, kfC3, ak, 0, 0, 0);
                }
                const int colr = rB + l16;
                const int aB = diB + colr + 4 * quad - 16;
#pragma unroll
                for (int i = 0; i < 4; ++i)
                    KDs[(aB + i) * 36 + colr] = f2bf(ak[i] * 0.125f);
            }
        }
        __builtin_amdgcn_s_setprio(0);
        __syncthreads();

        // ================= phase B =================
        // prefetch next tile's kf + pe staging reg (consumed next iteration)
        {
            const int r0n = (kt < 31) ? r0 + 32 : r0;
            kfC0 = *(const bf16x8*)(kb + (size_t)(r0n + l16) * 64 + quad * 8);
            kfC1 = *(const bf16x8*)(kb + (size_t)(r0n + l16) * 64 + 32 + quad * 8);
            kfC2 = *(const bf16x8*)(kb + (size_t)(r0n + 16 + l16) * 64 + quad * 8);
            kfC3 = *(const bf16x8*)(kb + (size_t)(r0n + 16 + l16) * 64 + 32 + quad * 8);
            // rows [pb', pb'+32) for next iteration's stage (pb' = pb0 - r0n).
            int ar = pb0 - r0n + strow;
            peReg = *(const uint4*)(peb + (size_t)ar * 64 + ((stp ^ (ar & 7)) << 3));
        }
        // v fragments for PV
        bf16x8 vvA[4];
#pragma unroll
        for (int jf = 0; jf < 4; ++jf)
            vvA[jf] = *(const bf16x8*)(vtb + (size_t)(16 * jf + l16) * S_SEQ +
                                       r0 + quad * 8);

        // gather bias (vector b64) + assemble scores (pure adds)
        float sc0[4], sc1[4];
        {
            uint2 qd2 = *(uint2*)&QDs[lL * 100 + sbQ + 28 - 4 * quad];
            uint2 kd2 = *(uint2*)&KDs[(lL + 15) * 36 + 4 * quad];
            float hm0 = fmaf(0.5f, hv0.x, mv0.x);
            float hm1 = fmaf(0.5f, hv0.y, mv0.y);
            float hm2 = fmaf(0.5f, hv0.z, mv0.z);
            float hm3 = fmaf(0.5f, hv0.w, mv0.w);
            sc0[0] = accS0[0] + bf2f((unsigned short)(qd2.y >> 16)) +
                     bf2f((unsigned short)(kd2.x & 0xffff)) + hm0;
            sc0[1] = accS0[1] + bf2f((unsigned short)(qd2.y & 0xffff)) +
                     bf2f((unsigned short)(kd2.x >> 16)) + hm1;
            sc0[2] = accS0[2] + bf2f((unsigned short)(qd2.x >> 16)) +
                     bf2f((unsigned short)(kd2.y & 0xffff)) + hm2;
            sc0[3] = accS0[3] + bf2f((unsigned short)(qd2.x & 0xffff)) +
                     bf2f((unsigned short)(kd2.y >> 16)) + hm3;
        }
        {
            uint2 qd2 = *(uint2*)&QDs[lL * 100 + sbQ + 12 - 4 * quad];
            uint2 kd2 = *(uint2*)&KDs[(lL + 15) * 36 + 16 + 4 * quad];
            float hm0 = fmaf(0.5f, hv1.x, mv1.x);
            float hm1 = fmaf(0.5f, hv1.y, mv1.y);
            float hm2 = fmaf(0.5f, hv1.z, mv1.z);
            float hm3 = fmaf(0.5f, hv1.w, mv1.w);
            sc1[0] = accS1[0] + bf2f((unsigned short)(qd2.y >> 16)) +
                     bf2f((unsigned short)(kd2.x & 0xffff)) + hm0;
            sc1[1] = accS1[1] + bf2f((unsigned short)(qd2.y & 0xffff)) +
                     bf2f((unsigned short)(kd2.x >> 16)) + hm1;
            sc1[2] = accS1[2] + bf2f((unsigned short)(qd2.x >> 16)) +
                     bf2f((unsigned short)(kd2.y & 0xffff)) + hm2;
            sc1[3] = accS1[3] + bf2f((unsigned short)(qd2.x & 0xffff)) +
                     bf2f((unsigned short)(kd2.y >> 16)) + hm3;
        }

        // ---- online softmax ----
        float mx = fmaxf(fmaxf(fmaxf(sc0[0], sc0[1]), fmaxf(sc0[2], sc0[3])),
                         fmaxf(fmaxf(sc1[0], sc1[1]), fmaxf(sc1[2], sc1[3])));
        mx = fmaxf(mx, __shfl_xor(mx, 16));
        mx = fmaxf(mx, __shfl_xor(mx, 32));
        const float m_new = fmaxf(m_run, mx);
        const float al = __expf(m_run - m_new);
        m_run = m_new;
        float rs = 0.f;
#pragma unroll
        for (int i = 0; i < 4; ++i) { sc0[i] = __expf(sc0[i] - m_new); rs += sc0[i]; }
#pragma unroll
        for (int i = 0; i < 4; ++i) { sc1[i] = __expf(sc1[i] - m_new); rs += sc1[i]; }
        rs += __shfl_xor(rs, 16);
        rs += __shfl_xor(rs, 32);
        lsum = lsum * al + rs;

        // ---- probs -> LDS (intra-wave only) ----
        {
            uint2 pw;
            pw.x = pack2bf(sc0[0], sc0[1]); pw.y = pack2bf(sc0[2], sc0[3]);
            *(uint2*)&ps[lL * 32 + (((quad >> 1) ^ swzl) << 3) + 4 * (quad & 1)] = pw;
            pw.x = pack2bf(sc1[0], sc1[1]); pw.y = pack2bf(sc1[2], sc1[3]);
            *(uint2*)&ps[lL * 32 + (((2 + (quad >> 1)) ^ swzl) << 3) + 4 * (quad & 1)] = pw;
        }

        // ---- PV ----
        const bf16x8 pf = *(const bf16x8*)&ps[lL * 32 + ((quad ^ swzl) << 3)];
        const float alv0 = __shfl(al, 4 * quad + 0);
        const float alv1 = __shfl(al, 4 * quad + 1);
        const float alv2 = __shfl(al, 4 * quad + 2);
        const float alv3 = __shfl(al, 4 * quad + 3);
#pragma unroll
        for (int jf = 0; jf < 4; ++jf) {
            f32x4 o = accO[jf];
            o[0] *= alv0; o[1] *= alv1; o[2] *= alv2; o[3] *= alv3;
            o = MFMA16(pf, vvA[jf], o, 0, 0, 0);
            accO[jf] = o;
        }

        sbP = (sbP - 32) & 127;
        sbQ -= 32; if (sbQ < 0) sbQ += 96;
        cQ -= 32; if (cQ < 0) cQ += 96;
    }

    // ---- epilogue ----
    const float ls0 = __shfl(lsum, 4 * quad + 0);
    const float ls1 = __shfl(lsum, 4 * quad + 1);
    const float ls2 = __shfl(lsum, 4 * quad + 2);
    const float ls3 = __shfl(lsum, 4 * quad + 3);
#pragma unroll
    for (int jf = 0; jf < 4; ++jf) {
        const size_t col = (size_t)h * 64 + 16 * jf + l16;
        float* ob = out + ((size_t)b * S_SEQ + l0 + 16 * w + 4 * quad) * 1024 + col;
        ob[0]        = accO[jf][0] / ls0;
        ob[1024]     = accO[jf][1] / ls1;
        ob[2048]     = accO[jf][2] / ls2;
        ob[3072]     = accO[jf][3] / ls3;
    }
}

extern "C" void kernel_launch(void* const* d_in, const int* in_sizes, int n_in,
                              void* d_out, int out_size, void* d_ws, size_t ws_size,
                              hipStream_t stream) {
    const float* hs   = (const float*)d_in[0];
    const float* mask = (const float*)d_in[1];
    const float* hyp  = (const float*)d_in[2];
    const float* Wq   = (const float*)d_in[3];
    const float* bq   = (const float*)d_in[4];
    const float* Wk   = (const float*)d_in[5];
    const float* bk   = (const float*)d_in[6];
    const float* Wv   = (const float*)d_in[7];
    const float* bv   = (const float*)d_in[8];
    const float* de   = (const float*)d_in[9];

    char* ws = (char*)d_ws;
    unsigned short* qw  = (unsigned short*)(ws);                    // 8 MB
    unsigned short* kw  = (unsigned short*)(ws + (8u << 20));       // 8 MB
    unsigned short* vtw = (unsigned short*)(ws + (16u << 20));      // 8 MB (v^T)
    unsigned short* hsb = (unsigned short*)(ws + (24u << 20));      // 8 MB
    unsigned short* wt  = (unsigned short*)(ws + (32u << 20));      // 6 MB
    unsigned short* peb = (unsigned short*)(ws + (38u << 20));      // 0.25 MB

    prep_kernel<<<dim3(CONV_BLKS + 768), 256, 0, stream>>>(hs, de, Wq, Wk, Wv,
                                                           hsb, peb, wt);
    qkv_mfma_kernel<<<dim3(8, 32, 3), 256, 0, stream>>>(hsb, wt, bq, bk, bv, qw, kw, vtw);
    attn_mfma_kernel<<<dim3(16, NHEAD, BATCH), 256, 0, stream>>>(
        qw, kw, vtw, peb, hyp, mask, (float*)d_out);
}